// Round 2
// baseline (267.514 us; speedup 1.0000x reference)
//
#include <hip/hip_runtime.h>

#define BB 8
#define NS 5
#define NQ 75
#define NG 4
#define NF 49
#define CDIM 64
#define MROWS 384      // 5*64 padded support rows + 64 padded query rows
#define QBASE 320      // first query row
#define ASTR 24        // shorts per row per k-chunk: 16 data + 8 pad = 48 B (16*odd -> min b128 conflicts)
#define NCHUNK 4       // K = 64 staged as 4 chunks of 16

typedef __attribute__((ext_vector_type(8))) short bf16x8;
typedef __attribute__((ext_vector_type(16))) float f32x16;

__device__ __forceinline__ float multi_gauss(float d2) {
    // sum_k exp(-2^k/8 * d2), k=0..4 == t + t^2 + t^4 + t^8 + t^16, t=exp(-d2/8)
    d2 = fmaxf(d2, 0.f);
    float e  = __expf(-0.125f * d2);
    float e2 = e * e, e4 = e2 * e2, e8 = e4 * e4, e16 = e8 * e8;
    return e + e2 + e4 + e8 + e16;
}

__device__ __forceinline__ unsigned short f2bf(float x) {
    union { float f; unsigned u; } c; c.f = x;
    unsigned r = c.u + 0x7FFFu + ((c.u >> 16) & 1u);   // round-to-nearest-even
    return (unsigned short)(r >> 16);
}
__device__ __forceinline__ float bf2f(unsigned short h) {
    union { float f; unsigned u; } c; c.u = ((unsigned)h) << 16; return c.f;
}
__device__ __forceinline__ float wred(float x) {
    for (int o = 32; o; o >>= 1) x += __shfl_down(x, o, 64);
    return x;
}

// ---------------------------------------------------------------------------
// Kernel 0: zero the output (harness poisons it before every launch)
// ---------------------------------------------------------------------------
__global__ void zero_out(float* __restrict__ out) {
    int i = blockIdx.x * 256 + threadIdx.x;
    if (i < BB * NQ * NS) out[i] = 0.f;
}

// ---------------------------------------------------------------------------
// Kernel 1: mmd_s contribution (beta^T Kss beta), VALU path (cheap: 160 matrices).
// Grid = 5 vchunks * 160 = 800 blocks. atomicAdd 0.25*val into out.
// ---------------------------------------------------------------------------
#define NFP  52
#define SSTR 68
#define KSTR 53
#define TILE_F4 784
#define VPERC 15

__global__ __launch_bounds__(192) void kernel_mmd_s(
    const float* __restrict__ sup, const float* __restrict__ beta,
    float* __restrict__ out)
{
    int blk = blockIdx.x;
    int g  = blk & 3;
    int s  = (blk >> 2) % NS;
    int b  = (blk / (NS * NG)) % BB;
    int vc = blk / (BB * NS * NG);

    __shared__ __align__(16) float S[NFP][SSTR];
    __shared__ float K[NFP][KSTR];
    __shared__ float ssq[NFP];

    int t = threadIdx.x;
    const float4* sp = (const float4*)(sup + (size_t)((b * NS + s) * NG + g) * (NF * CDIM));
    for (int k = t; k < TILE_F4; k += 192) {
        int i = k >> 4, c4 = k & 15;
        *(float4*)&S[i][c4 * 4] = sp[k];
    }
    if (t < 48) {
        int i = NF + t / 16, c4 = t % 16;
        *(float4*)&S[i][c4 * 4] = make_float4(0.f, 0.f, 0.f, 0.f);
    }
    __syncthreads();
    if (t < NFP) {
        float a = 0.f;
        for (int c = 0; c < CDIM; c += 4) {
            float4 x = *(float4*)&S[t][c];
            a += x.x * x.x + x.y * x.y + x.z * x.z + x.w * x.w;
        }
        ssq[t] = a;
    }
    __syncthreads();
    if (t < 169) {
        int ty = t / 13, tx = t - ty * 13;
        int i0 = ty * 4, j0 = tx * 4;
        float acc[4][4] = {};
        for (int c = 0; c < CDIM; c += 4) {
            float4 av[4], bv[4];
#pragma unroll
            for (int r = 0; r < 4; ++r) av[r] = *(float4*)&S[i0 + r][c];
#pragma unroll
            for (int u = 0; u < 4; ++u) bv[u] = *(float4*)&S[j0 + u][c];
#pragma unroll
            for (int r = 0; r < 4; ++r)
#pragma unroll
                for (int u = 0; u < 4; ++u)
                    acc[r][u] += av[r].x * bv[u].x + av[r].y * bv[u].y
                               + av[r].z * bv[u].z + av[r].w * bv[u].w;
        }
#pragma unroll
        for (int r = 0; r < 4; ++r)
#pragma unroll
            for (int u = 0; u < 4; ++u)
                K[i0 + r][j0 + u] = multi_gauss(ssq[i0 + r] + ssq[j0 + u] - 2.f * acc[r][u]);
    }
    __syncthreads();

    int wave = t >> 6, lane = t & 63;
    for (int vi = wave; vi < VPERC; vi += 3) {
        int v = vc * VPERC + vi;
        const float* bp = beta + (size_t)(((b * NQ + v) * NS + s) * NG + g) * NF;
        float part = 0.f;
        if (lane < NF) {
            float u = 0.f;
            for (int i = 0; i < NF; ++i) u = fmaf(bp[i], K[i][lane], u);
            part = u * bp[lane];
        }
        part = wred(part);
        if (lane == 0) atomicAdd(&out[(b * NQ + v) * NS + s], 0.25f * part);
    }
}

// ---------------------------------------------------------------------------
// Kernel 2: MFMA cross + qq.  One block per (b,v,g), 256 threads = 4 waves.
// A rows 0..319: support (s = row>>6, i = row&63, zero-pad i>=49)
// A rows 320..383: query rows (zero-pad j>=49)
// D = A . A[320:384]^T via 32x32x16 bf16 MFMA with hi/lo split (3 mfma/step).
// Epilogue: cross rows -> mmd_sq[s]; qq rows -> mmd_q[s] (all 5 s).
// atomicAdd 0.25*(mmd_q - 2*mmd_sq) into out[b,v,s].
// ---------------------------------------------------------------------------
__global__ __launch_bounds__(256) void mmd_cross(
    const float* __restrict__ sup, const float* __restrict__ qry,
    const float* __restrict__ beta, const float* __restrict__ gamma,
    float* __restrict__ out)
{
    int blk = blockIdx.x;
    int g = blk & 3;
    int v = (blk >> 2) % NQ;
    int b = blk / (NQ * NG);

    __shared__ __align__(16) short sAhi[MROWS * ASTR];
    __shared__ __align__(16) short sAlo[MROWS * ASTR];
    __shared__ float ssq[MROWS];
    __shared__ float sbeta[NS][64];
    __shared__ float sgam[NS][64];
    __shared__ float red_sq[NS], red_qq[NS];

    int t = threadIdx.x;
    int w = t >> 6, lane = t & 63, lrow = lane & 31, lhalf = lane >> 5;

    // zero ssq, stage beta/gamma (zero-padded)
    ssq[t] = 0.f;
    if (t < MROWS - 256) ssq[t + 256] = 0.f;
    for (int u = t; u < NS * 64; u += 256) {
        int s = u >> 6, i = u & 63;
        float bvv = 0.f, gvv = 0.f;
        if (i < NF) {
            size_t base = (size_t)(((b * NQ + v) * NS + s) * NG + g) * NF + i;
            bvv = beta[base];
            gvv = gamma[base];
        }
        sbeta[s][i] = bvv;
        sgam[s][i]  = gvv;
    }
    if (t < NS) { red_sq[t] = 0.f; red_qq[t] = 0.f; }

    // precompute staging sources: 1536 units = 384 rows x 4 float4-groups
    const float4* srcp[6];
    int rrow[6], kq4[6], ldso[6];
#pragma unroll
    for (int k = 0; k < 6; ++k) {
        int u = t + 256 * k;
        int r = u >> 2, kq = u & 3;
        rrow[k] = r; kq4[k] = kq;
        ldso[k] = r * ASTR + kq * 4;
        const float* rowbase = nullptr;
        if (r < QBASE) {
            int s = r >> 6, i = r & 63;
            if (i < NF) rowbase = sup + ((size_t)((b * NS + s) * NG + g) * NF + i) * CDIM;
        } else {
            int j = r - QBASE;
            if (j < NF) rowbase = qry + ((size_t)((b * NQ + v) * NG + g) * NF + j) * CDIM;
        }
        srcp[k] = (const float4*)rowbase;
    }

    f32x16 acc[3][2];
#pragma unroll
    for (int mi = 0; mi < 3; ++mi)
#pragma unroll
        for (int nt = 0; nt < 2; ++nt)
#pragma unroll
            for (int q = 0; q < 16; ++q) acc[mi][nt][q] = 0.f;

    for (int kc = 0; kc < NCHUNK; ++kc) {
        __syncthreads();   // previous MFMA reads done (and first-iter beta/gamma/ssq init)
#pragma unroll
        for (int k = 0; k < 6; ++k) {
            float4 x = make_float4(0.f, 0.f, 0.f, 0.f);
            if (srcp[k]) {
                x = srcp[k][kc * 4 + kq4[k]];
                atomicAdd(&ssq[rrow[k]], x.x * x.x + x.y * x.y + x.z * x.z + x.w * x.w);
            }
            short4 h4, l4;
            h4.x = (short)f2bf(x.x); l4.x = (short)f2bf(x.x - bf2f((unsigned short)h4.x));
            h4.y = (short)f2bf(x.y); l4.y = (short)f2bf(x.y - bf2f((unsigned short)h4.y));
            h4.z = (short)f2bf(x.z); l4.z = (short)f2bf(x.z - bf2f((unsigned short)h4.z));
            h4.w = (short)f2bf(x.w); l4.w = (short)f2bf(x.w - bf2f((unsigned short)h4.w));
            *(short4*)&sAhi[ldso[k]] = h4;
            *(short4*)&sAlo[ldso[k]] = l4;
        }
        __syncthreads();

        bf16x8 bh[2], bl[2];
#pragma unroll
        for (int nt = 0; nt < 2; ++nt) {
            int off = (QBASE + nt * 32 + lrow) * ASTR + lhalf * 8;
            bh[nt] = *(const bf16x8*)&sAhi[off];
            bl[nt] = *(const bf16x8*)&sAlo[off];
        }
#pragma unroll
        for (int mi = 0; mi < 3; ++mi) {
            int mt = w + 4 * mi;
            int aoff = (mt * 32 + lrow) * ASTR + lhalf * 8;
            bf16x8 ah = *(const bf16x8*)&sAhi[aoff];
            bf16x8 al = *(const bf16x8*)&sAlo[aoff];
#pragma unroll
            for (int nt = 0; nt < 2; ++nt) {
                acc[mi][nt] = __builtin_amdgcn_mfma_f32_32x32x16_bf16(ah, bh[nt], acc[mi][nt], 0, 0, 0);
                acc[mi][nt] = __builtin_amdgcn_mfma_f32_32x32x16_bf16(ah, bl[nt], acc[mi][nt], 0, 0, 0);
                acc[mi][nt] = __builtin_amdgcn_mfma_f32_32x32x16_bf16(al, bh[nt], acc[mi][nt], 0, 0, 0);
            }
        }
    }
    __syncthreads();   // ssq complete, reds zeroed, MFMAs done

    // epilogue: C/D layout (verified): col = lane&31, row = (reg&3) + 8*(reg>>2) + 4*(lane>>5)
    float qsqv0 = ssq[QBASE + lrow];
    float qsqv1 = ssq[QBASE + 32 + lrow];

#pragma unroll
    for (int mi = 0; mi < 3; ++mi) {
        int mt = w + 4 * mi;
        if (mt < 10) {                     // cross tile: s = mt>>1
            int s = mt >> 1;
            int ioff = (mt & 1) * 32;
            float gc0 = sgam[s][lrow], gc1 = sgam[s][32 + lrow];
            float tsum = 0.f;
#pragma unroll
            for (int reg = 0; reg < 16; ++reg) {
                int lr = (reg & 3) + 8 * (reg >> 2) + 4 * lhalf;
                float sq = ssq[mt * 32 + lr];
                float bv = sbeta[s][ioff + lr];
                float kv0 = multi_gauss(sq + qsqv0 - 2.f * acc[mi][0][reg]);
                float kv1 = multi_gauss(sq + qsqv1 - 2.f * acc[mi][1][reg]);
                tsum += bv * (gc0 * kv0 + gc1 * kv1);
            }
            tsum = wred(tsum);
            if (lane == 0) atomicAdd(&red_sq[s], tsum);
        } else {                           // qq tile
            int qoff = (mt - 10) * 32;
            float qs[NS] = {0.f, 0.f, 0.f, 0.f, 0.f};
            float gc0[NS], gc1[NS];
#pragma unroll
            for (int s = 0; s < NS; ++s) { gc0[s] = sgam[s][lrow]; gc1[s] = sgam[s][32 + lrow]; }
#pragma unroll
            for (int reg = 0; reg < 16; ++reg) {
                int lr = (reg & 3) + 8 * (reg >> 2) + 4 * lhalf;
                int i2 = qoff + lr;
                float sq = ssq[QBASE + i2];
                float kv0 = multi_gauss(sq + qsqv0 - 2.f * acc[mi][0][reg]);
                float kv1 = multi_gauss(sq + qsqv1 - 2.f * acc[mi][1][reg]);
#pragma unroll
                for (int s = 0; s < NS; ++s) {
                    float gi = sgam[s][i2];
                    qs[s] += gi * (gc0[s] * kv0 + gc1[s] * kv1);
                }
            }
#pragma unroll
            for (int s = 0; s < NS; ++s) {
                float r = wred(qs[s]);
                if (lane == 0) atomicAdd(&red_qq[s], r);
            }
        }
    }
    __syncthreads();
    if (t < NS)
        atomicAdd(&out[((size_t)b * NQ + v) * NS + t],
                  0.25f * (red_qq[t] - 2.f * red_sq[t]));
}

extern "C" void kernel_launch(void* const* d_in, const int* in_sizes, int n_in,
                              void* d_out, int out_size, void* d_ws, size_t ws_size,
                              hipStream_t stream) {
    const float* sup   = (const float*)d_in[0];
    const float* qry   = (const float*)d_in[1];
    const float* beta  = (const float*)d_in[2];
    const float* gamma = (const float*)d_in[3];
    float* out = (float*)d_out;

    zero_out<<<(BB * NQ * NS + 255) / 256, 256, 0, stream>>>(out);
    kernel_mmd_s<<<5 * BB * NS * NG, 192, 0, stream>>>(sup, beta, out);
    mmd_cross<<<BB * NQ * NG, 256, 0, stream>>>(sup, qry, beta, gamma, out);
}

// Round 3
// 158.309 us; speedup vs baseline: 1.6898x; 1.6898x over previous
//
#include <hip/hip_runtime.h>

#define BB 8
#define NS 5
#define NQ 75
#define NG 4
#define NF 49
#define CDIM 64

#define SUPROWS (BB * NG * NS * 64)     // 10240 rows
#define QRYROWS (BB * NQ * NG * 64)     // 153600 rows
#define TOTROWS (SUPROWS + QRYROWS)     // 163840 rows x 64 bf16

typedef __attribute__((ext_vector_type(8))) short bf16x8;
typedef __attribute__((ext_vector_type(16))) float f32x16;

__device__ __forceinline__ float multi_gauss(float d2) {
    // sum_k exp(-2^k/8 * d2), k=0..4 == t + t^2 + t^4 + t^8 + t^16, t=exp(-d2/8)
    d2 = fmaxf(d2, 0.f);
    float e  = __expf(-0.125f * d2);
    float e2 = e * e, e4 = e2 * e2, e8 = e4 * e4, e16 = e8 * e8;
    return e + e2 + e4 + e8 + e16;
}

__device__ __forceinline__ unsigned short f2bf(float x) {
    union { float f; unsigned u; } c; c.f = x;
    unsigned r = c.u + 0x7FFFu + ((c.u >> 16) & 1u);   // RNE
    return (unsigned short)(r >> 16);
}

__device__ __forceinline__ float wred(float x) {
    for (int o = 32; o; o >>= 1) x += __shfl_down(x, o, 64);
    return x;
}

// ---------------------------------------------------------------------------
// Kernel 0: zero the output (harness poisons it before every launch)
// ---------------------------------------------------------------------------
__global__ void zero_out(float* __restrict__ out) {
    int i = blockIdx.x * 256 + threadIdx.x;
    if (i < BB * NQ * NS) out[i] = 0.f;
}

// ---------------------------------------------------------------------------
// Kernel 1: prep — fp32 -> bf16 rows (zero-padded to 64 features) + fp32 ssq.
// ws row order: [sup: (b*NG+g)*320 + s*64 + i] then [qry: ((b*NQ+v)*NG+g)*64 + j]
// 32 threads per row, 2 channels each. Grid = TOTROWS*32/256 = 20480.
// ---------------------------------------------------------------------------
__global__ __launch_bounds__(256) void prep(
    const float* __restrict__ sup, const float* __restrict__ qry,
    unsigned short* __restrict__ whi, float* __restrict__ wssq)
{
    int u = blockIdx.x * 256 + threadIdx.x;
    int row = u >> 5;
    int c = (u & 31) * 2;

    const float* src = nullptr;
    if (row < SUPROWS) {
        int i = row & 63, t6 = row >> 6;
        int s = t6 % NS, bg = t6 / NS;
        int g = bg & 3, b = bg >> 2;
        if (i < NF) src = sup + ((size_t)(((b * NS + s) * NG + g) * NF + i)) * CDIM + c;
    } else {
        int r2 = row - SUPROWS;
        int j = r2 & 63, t6 = r2 >> 6;
        int g = t6 & 3, v = (t6 >> 2) % NQ, b = t6 / (NQ * NG);
        if (j < NF) src = qry + ((size_t)(((b * NQ + v) * NG + g) * NF + j)) * CDIM + c;
    }
    float x = 0.f, y = 0.f;
    if (src) { float2 xy = *(const float2*)src; x = xy.x; y = xy.y; }
    ushort2 h2; h2.x = f2bf(x); h2.y = f2bf(y);
    ((ushort2*)whi)[u] = h2;

    float v2 = x * x + y * y;
    for (int off = 16; off; off >>= 1) v2 += __shfl_down(v2, off, 64);
    if ((u & 31) == 0) wssq[row] = v2;   // lanes 0 and 32 hold their row's sum
}

// ---------------------------------------------------------------------------
// Kernel 2: mmd_s — beta^T Kss beta, exact fp32 (diagonal exactness matters).
// Grid = 3 vchunks * 160 (b,s,g) = 480 blocks, 256 threads, 25 v per block.
// ---------------------------------------------------------------------------
#define NFP  52
#define SSTR 68
#define KSTR 53
#define TILE_F4 784
#define VPERC 25

__global__ __launch_bounds__(256) void kernel_mmd_s(
    const float* __restrict__ sup, const float* __restrict__ beta,
    float* __restrict__ out)
{
    int blk = blockIdx.x;
    int g  = blk & 3;
    int s  = (blk >> 2) % NS;
    int b  = ((blk >> 2) / NS) % BB;
    int vc = blk / (BB * NS * NG);

    __shared__ __align__(16) float S[NFP][SSTR];
    __shared__ float K[NFP][KSTR];
    __shared__ float ssq[NFP];
    __shared__ float sbet[VPERC][NFP];

    int t = threadIdx.x;
    const float4* sp = (const float4*)(sup + (size_t)((b * NS + s) * NG + g) * (NF * CDIM));
    for (int k = t; k < TILE_F4; k += 256) {
        int i = k >> 4, c4 = k & 15;
        *(float4*)&S[i][c4 * 4] = sp[k];
    }
    if (t < 48) {  // zero pad rows 49..51
        int i = NF + t / 16, c4 = t % 16;
        *(float4*)&S[i][c4 * 4] = make_float4(0.f, 0.f, 0.f, 0.f);
    }
    for (int u = t; u < VPERC * NF; u += 256) {
        int vi = u / NF, i = u - vi * NF;
        int v = vc * VPERC + vi;
        sbet[vi][i] = beta[(size_t)(((b * NQ + v) * NS + s) * NG + g) * NF + i];
    }
    __syncthreads();
    if (t < NFP) {
        float a = 0.f;
        for (int c = 0; c < CDIM; c += 4) {
            float4 x = *(float4*)&S[t][c];
            a += x.x * x.x + x.y * x.y + x.z * x.z + x.w * x.w;
        }
        ssq[t] = a;
    }
    __syncthreads();
    if (t < 169) {
        int ty = t / 13, tx = t - ty * 13;
        int i0 = ty * 4, j0 = tx * 4;
        float acc[4][4] = {};
        for (int c = 0; c < CDIM; c += 4) {
            float4 av[4], bv[4];
#pragma unroll
            for (int r = 0; r < 4; ++r) av[r] = *(float4*)&S[i0 + r][c];
#pragma unroll
            for (int u2 = 0; u2 < 4; ++u2) bv[u2] = *(float4*)&S[j0 + u2][c];
#pragma unroll
            for (int r = 0; r < 4; ++r)
#pragma unroll
                for (int u2 = 0; u2 < 4; ++u2)
                    acc[r][u2] += av[r].x * bv[u2].x + av[r].y * bv[u2].y
                                + av[r].z * bv[u2].z + av[r].w * bv[u2].w;
        }
#pragma unroll
        for (int r = 0; r < 4; ++r)
#pragma unroll
            for (int u2 = 0; u2 < 4; ++u2)
                K[i0 + r][j0 + u2] = multi_gauss(ssq[i0 + r] + ssq[j0 + u2] - 2.f * acc[r][u2]);
    }
    __syncthreads();

    int w = t >> 6, lane = t & 63;
    for (int vi = w; vi < VPERC; vi += 4) {
        float part = 0.f;
        if (lane < NF) {
            float u2 = 0.f;
            for (int i = 0; i < NF; ++i) u2 = fmaf(sbet[vi][i], K[i][lane], u2);
            part = u2 * sbet[vi][lane];
        }
        part = wred(part);
        if (lane == 0) {
            int v = vc * VPERC + vi;
            atomicAdd(&out[(b * NQ + v) * NS + s], 0.25f * part);
        }
    }
}

// ---------------------------------------------------------------------------
// Kernel 3: MFMA cross + qq. One block per (b,v,g), 256 thr = 4 waves.
// Fragments loaded straight from ws (bf16, hi-only); NO LDS staging,
// NO barriers in the K-loop. qq diagonal fixed to exact K(0)=5.
// ---------------------------------------------------------------------------
__global__ __launch_bounds__(256) void mmd_cross(
    const unsigned short* __restrict__ whi, const float* __restrict__ wssq,
    const float* __restrict__ beta, const float* __restrict__ gamma,
    float* __restrict__ out)
{
    int blk = blockIdx.x;
    int g = blk & 3;
    int v = (blk >> 2) % NQ;
    int b = blk / (NQ * NG);

    __shared__ float sbeta[NS][64], sgam[NS][64];
    __shared__ float ssq[384];
    __shared__ float red_sq[NS], red_qq[NS];

    int t = threadIdx.x;
    int w = t >> 6, lane = t & 63, lrow = lane & 31, lhalf = lane >> 5;

    int srow0 = (b * NG + g) * (NS * 64);
    int qrow0 = SUPROWS + ((b * NQ + v) * NG + g) * 64;

    // stage ssq / beta / gamma / reduction slots (consumed only in epilogue)
    for (int u = t; u < 384; u += 256)
        ssq[u] = (u < 320) ? wssq[srow0 + u] : wssq[qrow0 + (u - 320)];
    for (int u = t; u < NS * 64; u += 256) {
        int s = u >> 6, i = u & 63;
        float bvv = 0.f, gvv = 0.f;
        if (i < NF) {
            size_t base = (size_t)(((b * NQ + v) * NS + s) * NG + g) * NF + i;
            bvv = beta[base]; gvv = gamma[base];
        }
        sbeta[s][i] = bvv; sgam[s][i] = gvv;
    }
    if (t < NS) { red_sq[t] = 0.f; red_qq[t] = 0.f; }

    const bf16x8* W = (const bf16x8*)whi;   // 8-short groups; row = 8 groups

    f32x16 acc[3][2];
#pragma unroll
    for (int mi = 0; mi < 3; ++mi)
#pragma unroll
        for (int nt = 0; nt < 2; ++nt)
#pragma unroll
            for (int q = 0; q < 16; ++q) acc[mi][nt][q] = 0.f;

    int a2row = (w < 2) ? (srow0 + (w + 8) * 32 + lrow)   // cross tiles 8,9
                        : (qrow0 + (w - 2) * 32 + lrow);  // qq tiles 10,11
#pragma unroll
    for (int kc = 0; kc < 4; ++kc) {
        int ko = kc * 2 + lhalf;
        bf16x8 bh0 = W[(qrow0 + lrow) * 8 + ko];
        bf16x8 bh1 = W[(qrow0 + 32 + lrow) * 8 + ko];
        bf16x8 a0  = W[(srow0 + w * 32 + lrow) * 8 + ko];
        bf16x8 a1  = W[(srow0 + (w + 4) * 32 + lrow) * 8 + ko];
        bf16x8 a2  = W[a2row * 8 + ko];
        acc[0][0] = __builtin_amdgcn_mfma_f32_32x32x16_bf16(a0, bh0, acc[0][0], 0, 0, 0);
        acc[0][1] = __builtin_amdgcn_mfma_f32_32x32x16_bf16(a0, bh1, acc[0][1], 0, 0, 0);
        acc[1][0] = __builtin_amdgcn_mfma_f32_32x32x16_bf16(a1, bh0, acc[1][0], 0, 0, 0);
        acc[1][1] = __builtin_amdgcn_mfma_f32_32x32x16_bf16(a1, bh1, acc[1][1], 0, 0, 0);
        acc[2][0] = __builtin_amdgcn_mfma_f32_32x32x16_bf16(a2, bh0, acc[2][0], 0, 0, 0);
        acc[2][1] = __builtin_amdgcn_mfma_f32_32x32x16_bf16(a2, bh1, acc[2][1], 0, 0, 0);
    }
    __syncthreads();   // LDS staging visible for epilogue

    float qsq0 = ssq[320 + lrow];
    float qsq1 = ssq[320 + 32 + lrow];

#pragma unroll
    for (int mi = 0; mi < 3; ++mi) {
        int mt = w + 4 * mi;
        if (mt < 10) {                     // cross tile: s = mt>>1
            int s = mt >> 1;
            int ioff = (mt & 1) * 32;
            float gc0 = sgam[s][lrow], gc1 = sgam[s][32 + lrow];
            float tsum = 0.f;
#pragma unroll
            for (int reg = 0; reg < 16; ++reg) {
                int lr = (reg & 3) + 8 * (reg >> 2) + 4 * lhalf;
                float sq = ssq[mt * 32 + lr];
                float bv = sbeta[s][ioff + lr];
                float kv0 = multi_gauss(sq + qsq0 - 2.f * acc[mi][0][reg]);
                float kv1 = multi_gauss(sq + qsq1 - 2.f * acc[mi][1][reg]);
                tsum += bv * (gc0 * kv0 + gc1 * kv1);
            }
            tsum = wred(tsum);
            if (lane == 0) atomicAdd(&red_sq[s], tsum);
        } else {                           // qq tile: A-rows are query rows
            int qoff = (mt - 10) * 32;
            float qs[NS] = {0.f, 0.f, 0.f, 0.f, 0.f};
            float gc0[NS], gc1[NS];
#pragma unroll
            for (int s = 0; s < NS; ++s) { gc0[s] = sgam[s][lrow]; gc1[s] = sgam[s][32 + lrow]; }
#pragma unroll
            for (int reg = 0; reg < 16; ++reg) {
                int lr = (reg & 3) + 8 * (reg >> 2) + 4 * lhalf;
                int i2 = qoff + lr;
                float sq = ssq[320 + i2];
                float kv0 = (i2 == lrow)      ? 5.0f
                          : multi_gauss(sq + qsq0 - 2.f * acc[mi][0][reg]);
                float kv1 = (i2 == 32 + lrow) ? 5.0f
                          : multi_gauss(sq + qsq1 - 2.f * acc[mi][1][reg]);
#pragma unroll
                for (int s = 0; s < NS; ++s) {
                    float gi = sgam[s][i2];
                    qs[s] += gi * (gc0[s] * kv0 + gc1[s] * kv1);
                }
            }
#pragma unroll
            for (int s = 0; s < NS; ++s) {
                float r = wred(qs[s]);
                if (lane == 0) atomicAdd(&red_qq[s], r);
            }
        }
    }
    __syncthreads();
    if (t < NS)
        atomicAdd(&out[((size_t)b * NQ + v) * NS + t],
                  0.25f * (red_qq[t] - 2.f * red_sq[t]));
}

extern "C" void kernel_launch(void* const* d_in, const int* in_sizes, int n_in,
                              void* d_out, int out_size, void* d_ws, size_t ws_size,
                              hipStream_t stream) {
    const float* sup   = (const float*)d_in[0];
    const float* qry   = (const float*)d_in[1];
    const float* beta  = (const float*)d_in[2];
    const float* gamma = (const float*)d_in[3];
    float* out = (float*)d_out;

    unsigned short* whi = (unsigned short*)d_ws;                 // TOTROWS*64 bf16 = 20.97 MB
    float* wssq = (float*)(whi + (size_t)TOTROWS * 64);          // TOTROWS floats = 0.66 MB

    zero_out<<<(BB * NQ * NS + 255) / 256, 256, 0, stream>>>(out);
    prep<<<(TOTROWS * 32) / 256, 256, 0, stream>>>(sup, qry, whi, wssq);
    kernel_mmd_s<<<3 * BB * NS * NG, 256, 0, stream>>>(sup, beta, out);
    mmd_cross<<<BB * NQ * NG, 256, 0, stream>>>(whi, wssq, beta, gamma, out);
}

// Round 4
// 146.450 us; speedup vs baseline: 1.8267x; 1.0810x over previous
//
#include <hip/hip_runtime.h>

#define BB 8
#define NS 5
#define NQ 75
#define NG 4
#define NF 49
#define CDIM 64

#define SUPROWS (BB * NG * NS * 64)     // 10240 rows
#define QRYROWS (BB * NQ * NG * 64)     // 153600 rows
#define TOTROWS (SUPROWS + QRYROWS)     // 163840 rows x 64 bf16
#define NOUT (BB * NQ * NS)             // 3000

typedef __attribute__((ext_vector_type(8))) short bf16x8;
typedef __attribute__((ext_vector_type(16))) float f32x16;

__device__ __forceinline__ float multi_gauss(float d2) {
    d2 = fmaxf(d2, 0.f);
    float e  = __expf(-0.125f * d2);
    float e2 = e * e, e4 = e2 * e2, e8 = e4 * e4, e16 = e8 * e8;
    return e + e2 + e4 + e8 + e16;
}

// scaled-domain variant: arg = -0.125*log2(e)*d2  (arg <= 0), K = t+t^2+t^4+t^8+t^16
__device__ __forceinline__ float multi_gauss2(float arg) {
    float e  = __builtin_amdgcn_exp2f(fminf(arg, 0.f));
    float e2 = e * e, e4 = e2 * e2, e8 = e4 * e4, e16 = e8 * e8;
    return ((e + e2) + (e4 + e8)) + e16;
}

__device__ __forceinline__ unsigned short f2bf(float x) {
    union { float f; unsigned u; } c; c.f = x;
    unsigned r = c.u + 0x7FFFu + ((c.u >> 16) & 1u);   // RNE
    return (unsigned short)(r >> 16);
}

__device__ __forceinline__ float wred(float x) {
    for (int o = 32; o; o >>= 1) x += __shfl_down(x, o, 64);
    return x;
}

// ---------------------------------------------------------------------------
// Kernel 1: prep — fp32 -> bf16 rows (zero-padded to 64 features) + fp32 ssq,
// and zero the 3000-float output (harness poisons it each launch).
// ---------------------------------------------------------------------------
__global__ __launch_bounds__(256) void prep(
    const float* __restrict__ sup, const float* __restrict__ qry,
    unsigned short* __restrict__ whi, float* __restrict__ wssq,
    float* __restrict__ out)
{
    int u = blockIdx.x * 256 + threadIdx.x;
    if (u < NOUT) out[u] = 0.f;

    int row = u >> 5;
    int c = (u & 31) * 2;

    const float* src = nullptr;
    if (row < SUPROWS) {
        int i = row & 63, t6 = row >> 6;
        int s = t6 % NS, bg = t6 / NS;
        int g = bg & 3, b = bg >> 2;
        if (i < NF) src = sup + ((size_t)(((b * NS + s) * NG + g) * NF + i)) * CDIM + c;
    } else {
        int r2 = row - SUPROWS;
        int j = r2 & 63, t6 = r2 >> 6;
        int g = t6 & 3, v = (t6 >> 2) % NQ, b = t6 / (NQ * NG);
        if (j < NF) src = qry + ((size_t)(((b * NQ + v) * NG + g) * NF + j)) * CDIM + c;
    }
    float x = 0.f, y = 0.f;
    if (src) { float2 xy = *(const float2*)src; x = xy.x; y = xy.y; }
    ushort2 h2; h2.x = f2bf(x); h2.y = f2bf(y);
    ((ushort2*)whi)[u] = h2;

    float v2 = x * x + y * y;
    for (int off = 16; off; off >>= 1) v2 += __shfl_down(v2, off, 64);
    if ((u & 31) == 0) wssq[row] = v2;   // lanes 0 and 32 hold their row's sum
}

// ---------------------------------------------------------------------------
// Kernel 2: mmd_s — beta^T Kss beta, exact fp32. 480 blocks, 25 v per block.
// ---------------------------------------------------------------------------
#define NFP  52
#define SSTR 68
#define KSTR 53
#define TILE_F4 784
#define VPERC 25

__global__ __launch_bounds__(256) void kernel_mmd_s(
    const float* __restrict__ sup, const float* __restrict__ beta,
    float* __restrict__ out)
{
    int blk = blockIdx.x;
    int g  = blk & 3;
    int s  = (blk >> 2) % NS;
    int b  = ((blk >> 2) / NS) % BB;
    int vc = blk / (BB * NS * NG);

    __shared__ __align__(16) float S[NFP][SSTR];
    __shared__ float K[NFP][KSTR];
    __shared__ float ssq[NFP];
    __shared__ float sbet[VPERC][NFP];

    int t = threadIdx.x;
    const float4* sp = (const float4*)(sup + (size_t)((b * NS + s) * NG + g) * (NF * CDIM));
    for (int k = t; k < TILE_F4; k += 256) {
        int i = k >> 4, c4 = k & 15;
        *(float4*)&S[i][c4 * 4] = sp[k];
    }
    if (t < 48) {
        int i = NF + t / 16, c4 = t % 16;
        *(float4*)&S[i][c4 * 4] = make_float4(0.f, 0.f, 0.f, 0.f);
    }
    for (int u = t; u < VPERC * NF; u += 256) {
        int vi = u / NF, i = u - vi * NF;
        int v = vc * VPERC + vi;
        sbet[vi][i] = beta[(size_t)(((b * NQ + v) * NS + s) * NG + g) * NF + i];
    }
    __syncthreads();
    if (t < NFP) {
        float a = 0.f;
        for (int c = 0; c < CDIM; c += 4) {
            float4 x = *(float4*)&S[t][c];
            a += x.x * x.x + x.y * x.y + x.z * x.z + x.w * x.w;
        }
        ssq[t] = a;
    }
    __syncthreads();
    if (t < 169) {
        int ty = t / 13, tx = t - ty * 13;
        int i0 = ty * 4, j0 = tx * 4;
        float acc[4][4] = {};
        for (int c = 0; c < CDIM; c += 4) {
            float4 av[4], bv[4];
#pragma unroll
            for (int r = 0; r < 4; ++r) av[r] = *(float4*)&S[i0 + r][c];
#pragma unroll
            for (int u2 = 0; u2 < 4; ++u2) bv[u2] = *(float4*)&S[j0 + u2][c];
#pragma unroll
            for (int r = 0; r < 4; ++r)
#pragma unroll
                for (int u2 = 0; u2 < 4; ++u2)
                    acc[r][u2] += av[r].x * bv[u2].x + av[r].y * bv[u2].y
                                + av[r].z * bv[u2].z + av[r].w * bv[u2].w;
        }
#pragma unroll
        for (int r = 0; r < 4; ++r)
#pragma unroll
            for (int u2 = 0; u2 < 4; ++u2)
                K[i0 + r][j0 + u2] = multi_gauss(ssq[i0 + r] + ssq[j0 + u2] - 2.f * acc[r][u2]);
    }
    __syncthreads();

    int w = t >> 6, lane = t & 63;
    for (int vi = w; vi < VPERC; vi += 4) {
        float part = 0.f;
        if (lane < NF) {
            float u2 = 0.f;
            for (int i = 0; i < NF; ++i) u2 = fmaf(sbet[vi][i], K[i][lane], u2);
            part = u2 * sbet[vi][lane];
        }
        part = wred(part);
        if (lane == 0) {
            int v = vc * VPERC + vi;
            atomicAdd(&out[(b * NQ + v) * NS + s], 0.25f * part);
        }
    }
}

// ---------------------------------------------------------------------------
// Kernel 3: MFMA cross + qq.  One block per (b,v,g,half): 4800 blocks, 4 waves.
// Per wave: 3 acc tiles (48 VGPR) -> higher occupancy than round-3's 6 tiles.
// m-tiles: {w, w+4} support-cross; third tile: w<2 -> support {8,9},
// w>=2 -> qq A-tile (w-2). B = query cols [h*32, h*32+32).
// ---------------------------------------------------------------------------
__global__ __launch_bounds__(256, 5) void mmd_cross(
    const unsigned short* __restrict__ whi, const float* __restrict__ wssq,
    const float* __restrict__ beta, const float* __restrict__ gamma,
    float* __restrict__ out)
{
    int blk = blockIdx.x;
    int h = blk & 1;
    int g = (blk >> 1) & 3;
    int v = (blk >> 3) % NQ;
    int b = blk / (NQ * NG * 2);

    __shared__ float sbeta[NS][64], sgam[NS][64];
    __shared__ float ssq[384];
    __shared__ float red_sq[NS], red_qq[NS];

    int t = threadIdx.x;
    int w = t >> 6, lane = t & 63, lrow = lane & 31, lhalf = lane >> 5;
    int qc = h * 32;                      // B column-tile offset within query rows

    int srow0 = (b * NG + g) * (NS * 64);
    int qrow0 = SUPROWS + ((b * NQ + v) * NG + g) * 64;

    for (int u = t; u < 384; u += 256)
        ssq[u] = (u < 320) ? wssq[srow0 + u] : wssq[qrow0 + (u - 320)];
    for (int u = t; u < NS * 64; u += 256) {
        int s = u >> 6, i = u & 63;
        float bvv = 0.f, gvv = 0.f;
        if (i < NF) {
            size_t base = (size_t)(((b * NQ + v) * NS + s) * NG + g) * NF + i;
            bvv = beta[base]; gvv = gamma[base];
        }
        sbeta[s][i] = bvv; sgam[s][i] = gvv;
    }
    if (t < NS) { red_sq[t] = 0.f; red_qq[t] = 0.f; }

    const bf16x8* W = (const bf16x8*)whi;

    f32x16 acc[3];
#pragma unroll
    for (int mi = 0; mi < 3; ++mi)
#pragma unroll
        for (int q = 0; q < 16; ++q) acc[mi][q] = 0.f;

    int a2row = (w < 2) ? (srow0 + (8 + w) * 32 + lrow)
                        : (qrow0 + (w - 2) * 32 + lrow);
#pragma unroll
    for (int kc = 0; kc < 4; ++kc) {
        int ko = kc * 2 + lhalf;
        bf16x8 bh = W[(qrow0 + qc + lrow) * 8 + ko];
        bf16x8 a0 = W[(srow0 + w * 32 + lrow) * 8 + ko];
        bf16x8 a1 = W[(srow0 + (w + 4) * 32 + lrow) * 8 + ko];
        bf16x8 a2 = W[a2row * 8 + ko];
        acc[0] = __builtin_amdgcn_mfma_f32_32x32x16_bf16(a0, bh, acc[0], 0, 0, 0);
        acc[1] = __builtin_amdgcn_mfma_f32_32x32x16_bf16(a1, bh, acc[1], 0, 0, 0);
        acc[2] = __builtin_amdgcn_mfma_f32_32x32x16_bf16(a2, bh, acc[2], 0, 0, 0);
    }
    __syncthreads();   // staging visible for epilogue

    const float c2  = -0.18033688f;   // -0.125 * log2(e)
    const float k2c =  0.36067376f;   // -2 * c2
    float qsq = ssq[320 + qc + lrow];
    float c2q = c2 * qsq;
    float gcol_q = sgam[0][qc + lrow]; // placeholder; per-s fetched below

#pragma unroll
    for (int mi = 0; mi < 3; ++mi) {
        int mt = (mi < 2) ? (w + 4 * mi) : ((w < 2) ? (8 + w) : -1);
        if (mt >= 0) {                 // cross tile: s = mt>>1, rows ioff..ioff+31
            int s = mt >> 1;
            int ioff = (mt & 1) * 32;
            float tsum = 0.f;
#pragma unroll
            for (int grp = 0; grp < 4; ++grp) {
                int rbase = grp * 8 + 4 * lhalf;
                float4 sqv = *(const float4*)&ssq[mt * 32 + rbase];
                float4 bvv = *(const float4*)&sbeta[s][ioff + rbase];
#pragma unroll
                for (int q = 0; q < 4; ++q) {
                    float sq = (q == 0) ? sqv.x : (q == 1) ? sqv.y : (q == 2) ? sqv.z : sqv.w;
                    float bv = (q == 0) ? bvv.x : (q == 1) ? bvv.y : (q == 2) ? bvv.z : bvv.w;
                    float arg = fmaf(k2c, acc[mi][grp * 4 + q], fmaf(c2, sq, c2q));
                    tsum = fmaf(bv, multi_gauss2(arg), tsum);
                }
            }
            tsum *= sgam[s][qc + lrow];          // gamma_j applied once
            tsum = wred(tsum);
            if (lane == 0) atomicAdd(&red_sq[s], tsum);
        } else {                       // qq tile: A = query rows [(w-2)*32, +32)
            int qoff = (w - 2) * 32;
            float qs[NS] = {0.f, 0.f, 0.f, 0.f, 0.f};
#pragma unroll
            for (int grp = 0; grp < 4; ++grp) {
                int rbase = grp * 8 + 4 * lhalf;
                float4 sqv = *(const float4*)&ssq[320 + qoff + rbase];
                float kvv[4];
#pragma unroll
                for (int q = 0; q < 4; ++q) {
                    float sq = (q == 0) ? sqv.x : (q == 1) ? sqv.y : (q == 2) ? sqv.z : sqv.w;
                    int row = qoff + rbase + q;
                    float arg = fmaf(k2c, acc[mi][grp * 4 + q], fmaf(c2, sq, c2q));
                    kvv[q] = (row == qc + lrow) ? 5.0f : multi_gauss2(arg);
                }
#pragma unroll
                for (int s = 0; s < NS; ++s) {
                    float4 gi = *(const float4*)&sgam[s][qoff + rbase];
                    qs[s] = fmaf(gi.x, kvv[0], qs[s]);
                    qs[s] = fmaf(gi.y, kvv[1], qs[s]);
                    qs[s] = fmaf(gi.z, kvv[2], qs[s]);
                    qs[s] = fmaf(gi.w, kvv[3], qs[s]);
                }
            }
#pragma unroll
            for (int s = 0; s < NS; ++s) {
                float r = wred(qs[s] * sgam[s][qc + lrow]);
                if (lane == 0) atomicAdd(&red_qq[s], r);
            }
        }
    }
    (void)gcol_q;
    __syncthreads();
    if (t < NS)
        atomicAdd(&out[((size_t)b * NQ + v) * NS + t],
                  0.25f * (red_qq[t] - 2.f * red_sq[t]));
}

extern "C" void kernel_launch(void* const* d_in, const int* in_sizes, int n_in,
                              void* d_out, int out_size, void* d_ws, size_t ws_size,
                              hipStream_t stream) {
    const float* sup   = (const float*)d_in[0];
    const float* qry   = (const float*)d_in[1];
    const float* beta  = (const float*)d_in[2];
    const float* gamma = (const float*)d_in[3];
    float* out = (float*)d_out;

    unsigned short* whi = (unsigned short*)d_ws;                 // TOTROWS*64 bf16 = 21 MB
    float* wssq = (float*)(whi + (size_t)TOTROWS * 64);          // TOTROWS floats

    prep<<<(TOTROWS * 32) / 256, 256, 0, stream>>>(sup, qry, whi, wssq, out);
    kernel_mmd_s<<<3 * BB * NS * NG, 256, 0, stream>>>(sup, beta, out);
    mmd_cross<<<BB * NQ * NG * 2, 256, 0, stream>>>(whi, wssq, beta, gamma, out);
}